// Round 6
// baseline (178.745 us; speedup 1.0000x reference)
//
#include <hip/hip_runtime.h>

// Tensor-train per-token contraction (fp32):
//   y[t,p,q,o] = relu(bias[p,q,o] + sum_{i,j,k,r,s} a[p,i,r] b[q,j,r,s] c[o,k,s] x[t,i,j,k])
// x: [65536,512] (i*64+j*8+k), out: [65536,1024] (p*128+q*16+o).
//
// TWO tokens per wave (8192 blocks x 4 waves), both x-loads issued up front
// (16 outstanding dwords) so token1's compute hides token0's store drain and
// the per-wave startup stall is amortized. Per-token body identical to R5:
//   A: lane=(j,k)=(hi,lo)  t1[p; r-pair]  64 pk_fma, 8x ds_write_b64
//   B: lane=(p,k)=(hi,lo)  t2[q; s-pair] 128 pk_fma, 8x b64 rd + 8x b64 wr
//   C: lane=(p,q)=(hi,lo)  y[o] 4-chunks, 128 pk_fma, 8x b64 rd, 4x b128 wr
//   store: 4x b128 rd + 4 coalesced 1KB global stores
// No barriers: each wave owns lds[w]; per-wave DS ops execute in order (this
// also orders token1's stage-A writes after token0's Y-reads).
// LDS layouts (dword units), bank-audited (free or 2-way=free):
//   T1 (p,r,j,k): p*128 + j*16 + k*2 + r
//   T2 (q,s,p,k): q*128 + p*16 + ((k^q)<<1) + s   (XOR applied via base^(q<<1))
//   Y  (p,q,m):   p*128 + q*16 + ((m^((q>>1)&3))<<2)

typedef float f32x2 __attribute__((ext_vector_type(2)));
typedef float f32x4 __attribute__((ext_vector_type(4)));

#define NTOK (16 * 4096)

static __device__ __forceinline__ f32x2 mk2(float a, float b) {
    f32x2 r; r.x = a; r.y = b; return r;
}

static __device__ __forceinline__ void token_body(
    float* __restrict__ buf,
    const float* __restrict__ a, const float* __restrict__ b,
    const float* __restrict__ c, const float* __restrict__ bias,
    float* __restrict__ out,
    int t, int l, int hi, int lo, const float (&xi)[8])
{
    // ---------------- Stage A: t1[p,r] = sum_i a[p,i,r] x[i,j,k] ----------
    {
        float* wA = buf + hi * 16 + lo * 2;
#pragma unroll
        for (int p = 0; p < 8; ++p) {
            f32x2 acc = mk2(0.f, 0.f);
#pragma unroll
            for (int i = 0; i < 8; ++i) {
                f32x2 A2 = *(const f32x2*)(a + p * 16 + i * 2);   // (r0,r1)
                acc = __builtin_elementwise_fma(A2, mk2(xi[i], xi[i]), acc);
            }
            *(f32x2*)(wA + p * 128) = acc;
        }
    }

    // ---------------- Stage B: t2[q,s] = sum_{j,r} b[q,j,r,s] t1[p,r,j,k] --
    {
        const float* rB = buf + hi * 128 + lo * 2;   // + j*16 (2-way, free)
        f32x2 u2[8];
#pragma unroll
        for (int j = 0; j < 8; ++j)
            u2[j] = *(const f32x2*)(rB + j * 16);

        const int wBb = hi * 16 + lo * 2;            // bits1-3 = k
#pragma unroll
        for (int q = 0; q < 8; ++q) {
            f32x2 acc = mk2(0.f, 0.f);               // (s0,s1)
#pragma unroll
            for (int j = 0; j < 8; ++j) {
                f32x2 B0 = *(const f32x2*)(b + q * 32 + j * 4 + 0); // r=0
                f32x2 B1 = *(const f32x2*)(b + q * 32 + j * 4 + 2); // r=1
                acc = __builtin_elementwise_fma(B0, mk2(u2[j].x, u2[j].x), acc);
                acc = __builtin_elementwise_fma(B1, mk2(u2[j].y, u2[j].y), acc);
            }
            *(f32x2*)(buf + ((wBb ^ (q << 1)) + q * 128)) = acc;
        }
    }

    // ---------------- Stage C: lane=(p=hi, q=lo) --------------------------
    {
        const int rCb = lo * 128 + hi * 16 + lo * 2; // bits1-3 = q
        f32x2 v2[8];
#pragma unroll
        for (int k = 0; k < 8; ++k)
            v2[k] = *(const f32x2*)(buf + (rCb ^ (k << 1)));

        const float* bb = bias + l * 16;             // (p*8+q)*16 = l*16
        float* wY = buf + hi * 128 + lo * 16;
        const int ysw = (lo >> 1) & 3;
#pragma unroll
        for (int m = 0; m < 4; ++m) {
            f32x4 bv4 = *(const f32x4*)(bb + m * 4);
            float yg[4];
#pragma unroll
            for (int oo = 0; oo < 4; ++oo) {
                const int o = m * 4 + oo;
                f32x2 acc = mk2(bv4[oo], 0.f);
#pragma unroll
                for (int k = 0; k < 8; ++k) {
                    f32x2 C2 = *(const f32x2*)(c + o * 16 + k * 2); // (s0,s1)
                    acc = __builtin_elementwise_fma(C2, v2[k], acc);
                }
                float v = acc.x + acc.y;
                yg[oo] = v > 0.f ? v : 0.f;
            }
            f32x4 yv; yv.x = yg[0]; yv.y = yg[1]; yv.z = yg[2]; yv.w = yg[3];
            *(f32x4*)(wY + ((m ^ ysw) << 2)) = yv;
        }
    }

    // ---------------- coalesced store ------------------------------------
    {
        const int base_r = (l >> 5) * 128 + ((l >> 2) & 7) * 16 +
                           (((l & 3) ^ ((l >> 3) & 3)) << 2);
        float* op = out + (size_t)t * 1024 + l * 4;
#pragma unroll
        for (int m = 0; m < 4; ++m) {
            f32x4 v = *(const f32x4*)(buf + base_r + m * 256);
            *(f32x4*)(op + m * 256) = v;
        }
    }
}

__global__ __launch_bounds__(256, 6) void tt_kernel(
    const float* __restrict__ x,
    const float* __restrict__ a,    // [8][8][2]    p,i,r
    const float* __restrict__ b,    // [8][8][2][2] q,j,r,s
    const float* __restrict__ c,    // [16][8][2]   o,k,s
    const float* __restrict__ bias, // [8][8][16]   p,q,o
    float* __restrict__ out)
{
    __shared__ alignas(16) float lds[4][1024];
    const int l = threadIdx.x & 63;
    const int w = threadIdx.x >> 6;
    float* buf = lds[w];
    const int t0 = blockIdx.x * 8 + w * 2;   // this wave's two tokens
    const int hi = l >> 3;
    const int lo = l & 7;

    // Issue BOTH tokens' x-loads up front: 16 outstanding coalesced dwords.
    const float* xp0 = x + (size_t)t0 * 512 + l;
    float xi0[8], xi1[8];
#pragma unroll
    for (int i = 0; i < 8; ++i) xi0[i] = xp0[i * 64];
#pragma unroll
    for (int i = 0; i < 8; ++i) xi1[i] = xp0[512 + i * 64];

    token_body(buf, a, b, c, bias, out, t0,     l, hi, lo, xi0);
    token_body(buf, a, b, c, bias, out, t0 + 1, l, hi, lo, xi1);
}

extern "C" void kernel_launch(void* const* d_in, const int* in_sizes, int n_in,
                              void* d_out, int out_size, void* d_ws, size_t ws_size,
                              hipStream_t stream) {
    const float* x    = (const float*)d_in[0];
    const float* a    = (const float*)d_in[1];
    const float* b    = (const float*)d_in[2];
    const float* c    = (const float*)d_in[3];
    const float* bias = (const float*)d_in[4];
    float* out = (float*)d_out;

    tt_kernel<<<NTOK / 8, 256, 0, stream>>>(x, a, b, c, bias, out);
}

// Round 8
// 93.545 us; speedup vs baseline: 1.9108x; 1.9108x over previous
//
#include <hip/hip_runtime.h>

// Tensor-train per-token contraction (fp32):
//   y[t,p,q,o] = relu(bias[p,q,o] + sum_{i,j,k,r,s} a[p,i,r] b[q,j,r,s] c[o,k,s] x[t,i,j,k])
// x: [65536,512] (i*64+j*8+k), out: [65536,1024] (p*128+q*16+o).
//
// TWO tokens per wave (macro-expanded R5 body; R6's fn-param version spilled).
// R7 LESSON: wave-level LDS stage boundaries (A-writes->B-reads,
// B-writes->C-reads, Y-writes->store-reads, store-reads->next-token-A-writes)
// have NO per-thread data dependency, so the scheduler may reorder DS ops
// across them -> cross-lane race (R7 absmax 0.2). Fix: compiler-only fences
// asm volatile(""::: "memory") at each boundary. R2 vs R4 measured these as
// performance-neutral (both 136us on identical structure).
// Per-token body (R5 = 90.7us):
//   A: lane=(j,k)=(hi,lo)  t1[p; r-pair]  64 pk_fma, 8x ds_write_b64
//   B: lane=(p,k)=(hi,lo)  t2[q; s-pair] 128 pk_fma, 8x b64 rd + 8x b64 wr
//   C: lane=(p,q)=(hi,lo)  y[o] 4-chunks, 128 pk_fma, 8x b64 rd, 4x b128 wr
//   store: 4x b128 rd + 4 coalesced 1KB global stores
// LDS layouts (dword units), bank-audited (free or 2-way=free):
//   T1 (p,r,j,k): p*128 + j*16 + k*2 + r
//   T2 (q,s,p,k): q*128 + p*16 + ((k^q)<<1) + s   (XOR applied via base^(q<<1))
//   Y  (p,q,m):   p*128 + q*16 + ((m^((q>>1)&3))<<2)

typedef float f32x2 __attribute__((ext_vector_type(2)));
typedef float f32x4 __attribute__((ext_vector_type(4)));

#define NTOK (16 * 4096)
#define LDS_FENCE() asm volatile("" ::: "memory")

static __device__ __forceinline__ f32x2 mk2(float a, float b) {
    f32x2 r; r.x = a; r.y = b; return r;
}

#define TOKEN_BODY(XI, T)                                                      \
  {                                                                            \
    /* Stage A: t1[p,r] = sum_i a[p,i,r] x[i,j,k] */                           \
    {                                                                          \
      float* wA = buf + hi * 16 + lo * 2;                                      \
      _Pragma("unroll")                                                        \
      for (int p = 0; p < 8; ++p) {                                            \
        f32x2 acc = mk2(0.f, 0.f);                                             \
        _Pragma("unroll")                                                      \
        for (int i = 0; i < 8; ++i) {                                          \
          f32x2 A2 = *(const f32x2*)(a + p * 16 + i * 2);                      \
          acc = __builtin_elementwise_fma(A2, mk2(XI[i], XI[i]), acc);         \
        }                                                                      \
        *(f32x2*)(wA + p * 128) = acc;                                         \
      }                                                                        \
    }                                                                          \
    LDS_FENCE(); /* A-writes -> B-reads */                                     \
    /* Stage B: t2[q,s] = sum_{j,r} b[q,j,r,s] t1[p,r,j,k] */                  \
    {                                                                          \
      const float* rB = buf + hi * 128 + lo * 2;                               \
      f32x2 u2[8];                                                             \
      _Pragma("unroll")                                                        \
      for (int j = 0; j < 8; ++j) u2[j] = *(const f32x2*)(rB + j * 16);        \
      const int wBb = hi * 16 + lo * 2;                                        \
      _Pragma("unroll")                                                        \
      for (int q = 0; q < 8; ++q) {                                            \
        f32x2 acc = mk2(0.f, 0.f);                                             \
        _Pragma("unroll")                                                      \
        for (int j = 0; j < 8; ++j) {                                          \
          f32x2 B0 = *(const f32x2*)(b + q * 32 + j * 4 + 0);                  \
          f32x2 B1 = *(const f32x2*)(b + q * 32 + j * 4 + 2);                  \
          acc = __builtin_elementwise_fma(B0, mk2(u2[j].x, u2[j].x), acc);     \
          acc = __builtin_elementwise_fma(B1, mk2(u2[j].y, u2[j].y), acc);     \
        }                                                                      \
        *(f32x2*)(buf + ((wBb ^ (q << 1)) + q * 128)) = acc;                   \
      }                                                                        \
    }                                                                          \
    LDS_FENCE(); /* B T2-writes -> C T2-reads */                               \
    /* Stage C: lane=(p=hi, q=lo) */                                           \
    {                                                                          \
      const int rCb = lo * 128 + hi * 16 + lo * 2;                             \
      f32x2 v2[8];                                                             \
      _Pragma("unroll")                                                        \
      for (int k = 0; k < 8; ++k)                                              \
        v2[k] = *(const f32x2*)(buf + (rCb ^ (k << 1)));                       \
      const float* bb = bias + l * 16;                                         \
      float* wY = buf + hi * 128 + lo * 16;                                    \
      const int ysw = (lo >> 1) & 3;                                           \
      _Pragma("unroll")                                                        \
      for (int m = 0; m < 4; ++m) {                                            \
        f32x4 bv4 = *(const f32x4*)(bb + m * 4);                               \
        float yg[4];                                                           \
        _Pragma("unroll")                                                      \
        for (int oo = 0; oo < 4; ++oo) {                                       \
          const int o = m * 4 + oo;                                            \
          f32x2 acc = mk2(bv4[oo], 0.f);                                       \
          _Pragma("unroll")                                                    \
          for (int k = 0; k < 8; ++k) {                                        \
            f32x2 C2 = *(const f32x2*)(c + o * 16 + k * 2);                    \
            acc = __builtin_elementwise_fma(C2, v2[k], acc);                   \
          }                                                                    \
          float vv = acc.x + acc.y;                                            \
          yg[oo] = vv > 0.f ? vv : 0.f;                                        \
        }                                                                      \
        f32x4 yv; yv.x = yg[0]; yv.y = yg[1]; yv.z = yg[2]; yv.w = yg[3];      \
        *(f32x4*)(wY + ((m ^ ysw) << 2)) = yv;                                 \
      }                                                                        \
    }                                                                          \
    LDS_FENCE(); /* Y-writes -> store-reads */                                 \
    /* coalesced store */                                                      \
    {                                                                          \
      const int base_r = (l >> 5) * 128 + ((l >> 2) & 7) * 16 +                \
                         (((l & 3) ^ ((l >> 3) & 3)) << 2);                    \
      float* op = out + (size_t)(T) * 1024 + l * 4;                            \
      _Pragma("unroll")                                                        \
      for (int m = 0; m < 4; ++m) {                                            \
        f32x4 v = *(const f32x4*)(buf + base_r + m * 256);                     \
        *(f32x4*)(op + m * 256) = v;                                           \
      }                                                                        \
    }                                                                          \
    LDS_FENCE(); /* store-reads -> next token's A-writes */                    \
  }

__global__ __launch_bounds__(256, 6) void tt_kernel(
    const float* __restrict__ x,
    const float* __restrict__ a,    // [8][8][2]    p,i,r
    const float* __restrict__ b,    // [8][8][2][2] q,j,r,s
    const float* __restrict__ c,    // [16][8][2]   o,k,s
    const float* __restrict__ bias, // [8][8][16]   p,q,o
    float* __restrict__ out)
{
    __shared__ alignas(16) float lds[4][1024];
    const int l = threadIdx.x & 63;
    const int w = threadIdx.x >> 6;
    float* buf = lds[w];
    const int t0 = blockIdx.x * 8 + w * 2;   // this wave's two tokens
    const int hi = l >> 3;
    const int lo = l & 7;

    // Issue BOTH tokens' x-loads up front: 16 outstanding coalesced dwords.
    const float* xp0 = x + (size_t)t0 * 512 + l;
    float xi0[8], xi1[8];
#pragma unroll
    for (int i = 0; i < 8; ++i) xi0[i] = xp0[i * 64];
#pragma unroll
    for (int i = 0; i < 8; ++i) xi1[i] = xp0[512 + i * 64];

    TOKEN_BODY(xi0, t0)
    TOKEN_BODY(xi1, t0 + 1)
}

extern "C" void kernel_launch(void* const* d_in, const int* in_sizes, int n_in,
                              void* d_out, int out_size, void* d_ws, size_t ws_size,
                              hipStream_t stream) {
    const float* x    = (const float*)d_in[0];
    const float* a    = (const float*)d_in[1];
    const float* b    = (const float*)d_in[2];
    const float* c    = (const float*)d_in[3];
    const float* bias = (const float*)d_in[4];
    float* out = (float*)d_out;

    tt_kernel<<<NTOK / 8, 256, 0, stream>>>(x, a, b, c, bias, out);
}

// Round 9
// 89.753 us; speedup vs baseline: 1.9915x; 1.0423x over previous
//
#include <hip/hip_runtime.h>

// Tensor-train per-token contraction (fp32):
//   y[t,p,q,o] = relu(bias[p,q,o] + sum_{i,j,k,r,s} a[p,i,r] b[q,j,r,s] c[o,k,s] x[t,i,j,k])
// x: [65536,512] (i*64+j*8+k), out: [65536,1024] (p*128+q*16+o).
//
// ONE token per wave (R5 structure, 90.7us champion), with:
//  - R7-lesson fences: compiler-only asm-memory fences at the 3 wave-level
//    LDS stage boundaries (A-wr->B-rd, B-wr->C-rd, Y-wr->Y-rd). These
//    boundaries have no per-thread dependency and race without them
//    (R7: absmax 0.2). Measured cost ~3% (R8 vs R5).
//  - __launch_bounds__(256, 8): cap allocator at 64 VGPR. gfx950 occupancy
//    steps at 64/128/256 regs (8/4/2 waves per SIMD); R5 was likely 65-84
//    VGPR -> 4 waves/SIMD -> the ~600cyc/token LDS-latency chain and 900cyc
//    HBM load latency only half-hidden (62% HBM duty). 8 waves/SIMD doubles
//    latency hiding. Peak live set ~40 regs, should fit without spill.
// Per-token body:
//   A: lane=(j,k)=(hi,lo)  t1[p; r-pair]  64 pk_fma, 8x ds_write_b64
//   B: lane=(p,k)=(hi,lo)  t2[q; s-pair] 128 pk_fma, 8x b64 rd + 8x b64 wr
//   C: lane=(p,q)=(hi,lo)  y[o] 4-chunks, 128 pk_fma, 8x b64 rd, 4x b128 wr
//   store: 4x b128 rd + 4 coalesced 1KB global stores
// LDS layouts (dword units), bank-audited (free or 2-way=free):
//   T1 (p,r,j,k): p*128 + j*16 + k*2 + r
//   T2 (q,s,p,k): q*128 + p*16 + ((k^q)<<1) + s   (XOR applied via base^(q<<1))
//   Y  (p,q,m):   p*128 + q*16 + ((m^((q>>1)&3))<<2)

typedef float f32x2 __attribute__((ext_vector_type(2)));
typedef float f32x4 __attribute__((ext_vector_type(4)));

#define NTOK (16 * 4096)
#define LDS_FENCE() asm volatile("" ::: "memory")

static __device__ __forceinline__ f32x2 mk2(float a, float b) {
    f32x2 r; r.x = a; r.y = b; return r;
}

__global__ __launch_bounds__(256, 8) void tt_kernel(
    const float* __restrict__ x,
    const float* __restrict__ a,    // [8][8][2]    p,i,r
    const float* __restrict__ b,    // [8][8][2][2] q,j,r,s
    const float* __restrict__ c,    // [16][8][2]   o,k,s
    const float* __restrict__ bias, // [8][8][16]   p,q,o
    float* __restrict__ out)
{
    __shared__ alignas(16) float lds[4][1024];
    const int l = threadIdx.x & 63;
    const int w = threadIdx.x >> 6;
    float* buf = lds[w];
    const int t = blockIdx.x * 4 + w;

    const int hi = l >> 3;   // A: j | B: p | C: p
    const int lo = l & 7;    // A: k | B: k | C: q

    // ---------------- load x: lane holds x[i, j=hi, k=lo] ----------------
    const float* xp = x + (size_t)t * 512 + l;
    float xi[8];
#pragma unroll
    for (int i = 0; i < 8; ++i) xi[i] = xp[i * 64];

    // ---------------- Stage A: t1[p,r] = sum_i a[p,i,r] x[i,j,k] ----------
    {
        float* wA = buf + hi * 16 + lo * 2;
#pragma unroll
        for (int p = 0; p < 8; ++p) {
            f32x2 acc = mk2(0.f, 0.f);
#pragma unroll
            for (int i = 0; i < 8; ++i) {
                f32x2 A2 = *(const f32x2*)(a + p * 16 + i * 2);   // (r0,r1)
                acc = __builtin_elementwise_fma(A2, mk2(xi[i], xi[i]), acc);
            }
            *(f32x2*)(wA + p * 128) = acc;
        }
    }
    LDS_FENCE(); // A-writes -> B-reads (wave-level, no per-thread dep)

    // ---------------- Stage B: t2[q,s] = sum_{j,r} b[q,j,r,s] t1[p,r,j,k] --
    {
        const float* rB = buf + hi * 128 + lo * 2;   // + j*16 (2-way, free)
        f32x2 u2[8];
#pragma unroll
        for (int j = 0; j < 8; ++j)
            u2[j] = *(const f32x2*)(rB + j * 16);

        const int wBb = hi * 16 + lo * 2;            // bits1-3 = k
#pragma unroll
        for (int q = 0; q < 8; ++q) {
            f32x2 acc = mk2(0.f, 0.f);               // (s0,s1)
#pragma unroll
            for (int j = 0; j < 8; ++j) {
                f32x2 B0 = *(const f32x2*)(b + q * 32 + j * 4 + 0); // r=0
                f32x2 B1 = *(const f32x2*)(b + q * 32 + j * 4 + 2); // r=1
                acc = __builtin_elementwise_fma(B0, mk2(u2[j].x, u2[j].x), acc);
                acc = __builtin_elementwise_fma(B1, mk2(u2[j].y, u2[j].y), acc);
            }
            *(f32x2*)(buf + ((wBb ^ (q << 1)) + q * 128)) = acc;
        }
    }
    LDS_FENCE(); // B T2-writes -> C T2-reads

    // ---------------- Stage C: lane=(p=hi, q=lo) --------------------------
    {
        const int rCb = lo * 128 + hi * 16 + lo * 2; // bits1-3 = q
        f32x2 v2[8];
#pragma unroll
        for (int k = 0; k < 8; ++k)
            v2[k] = *(const f32x2*)(buf + (rCb ^ (k << 1)));

        const float* bb = bias + l * 16;             // (p*8+q)*16 = l*16
        float* wY = buf + hi * 128 + lo * 16;
        const int ysw = (lo >> 1) & 3;
#pragma unroll
        for (int m = 0; m < 4; ++m) {
            f32x4 bv4 = *(const f32x4*)(bb + m * 4);
            float yg[4];
#pragma unroll
            for (int oo = 0; oo < 4; ++oo) {
                const int o = m * 4 + oo;
                f32x2 acc = mk2(bv4[oo], 0.f);
#pragma unroll
                for (int k = 0; k < 8; ++k) {
                    f32x2 C2 = *(const f32x2*)(c + o * 16 + k * 2); // (s0,s1)
                    acc = __builtin_elementwise_fma(C2, v2[k], acc);
                }
                float v = acc.x + acc.y;
                yg[oo] = v > 0.f ? v : 0.f;
            }
            f32x4 yv; yv.x = yg[0]; yv.y = yg[1]; yv.z = yg[2]; yv.w = yg[3];
            *(f32x4*)(wY + ((m ^ ysw) << 2)) = yv;
        }
    }
    LDS_FENCE(); // Y-writes -> Y-reads

    // ---------------- coalesced store ------------------------------------
    {
        const int base_r = (l >> 5) * 128 + ((l >> 2) & 7) * 16 +
                           (((l & 3) ^ ((l >> 3) & 3)) << 2);
        float* op = out + (size_t)t * 1024 + l * 4;
#pragma unroll
        for (int m = 0; m < 4; ++m) {
            f32x4 v = *(const f32x4*)(buf + base_r + m * 256);
            *(f32x4*)(op + m * 256) = v;
        }
    }
}

extern "C" void kernel_launch(void* const* d_in, const int* in_sizes, int n_in,
                              void* d_out, int out_size, void* d_ws, size_t ws_size,
                              hipStream_t stream) {
    const float* x    = (const float*)d_in[0];
    const float* a    = (const float*)d_in[1];
    const float* b    = (const float*)d_in[2];
    const float* c    = (const float*)d_in[3];
    const float* bias = (const float*)d_in[4];
    float* out = (float*)d_out;

    tt_kernel<<<NTOK / 4, 256, 0, stream>>>(x, a, b, c, bias, out);
}